// Round 5
// baseline (706.493 us; speedup 1.0000x reference)
//
#include <hip/hip_runtime.h>
#include <math.h>

// Problem constants
constexpr int kB    = 64;
constexpr int kN    = 32;
constexpr int kDIN  = 128;
constexpr int kH    = 256;
constexpr int kG4   = 1024;   // 4*H
constexpr int kDOUT = 128;
constexpr int kBN   = 2048;   // B*N

typedef __attribute__((ext_vector_type(8))) short bf16x8;
typedef __attribute__((ext_vector_type(4))) float f32x4;

__device__ __forceinline__ float sigm(float x) {
    return 1.0f / (1.0f + expf(-x));
}

// fp32 -> bf16 bits, round-to-nearest-even
__device__ __forceinline__ short f2bf(float f) {
    union { float f; unsigned u; } v; v.f = f;
    unsigned r = v.u + 0x7fffu + ((v.u >> 16) & 1u);
    return (short)(r >> 16);
}
__device__ __forceinline__ float bf2f(short s) {
    union { unsigned u; float f; } v;
    v.u = ((unsigned)(unsigned short)s) << 16;
    return v.f;
}

// ---------------------------------------------------------------------------
// K0 prep (one launch, 448 blocks, dim3(32,8)):
//   [0,64)    convert W_ih_f (1024x128) -> bf16, same [gate][k] layout
//   [64,128)  convert W_ih_r            -> bf16
//   [128,256) convert W_hh_f (1024x256) -> bf16, same [gate][k] layout
//   [256,384) convert W_hh_r            -> bf16
//   [384,448) transpose W_fc (128x512)  -> WfcT [k][dout] fp32
// ---------------------------------------------------------------------------
__global__ __launch_bounds__(256) void prep_k(
    const float* __restrict__ Wihf, const float* __restrict__ Wihr,
    const float* __restrict__ Whhf, const float* __restrict__ Whhr,
    const float* __restrict__ Wfc,
    short* __restrict__ Wih_bf_f, short* __restrict__ Wih_bf_r,
    short* __restrict__ Whh_bf_f, short* __restrict__ Whh_bf_r,
    float* __restrict__ WfcT)
{
    const int bx  = blockIdx.x;
    const int tid = threadIdx.y * 32 + threadIdx.x;
    if (bx < 384) {
        const float* src; short* dst; int lb;
        if (bx < 64)       { src = Whhf; dst = Whh_bf_f; lb = 0; }   // placeholder
        if (bx < 64)       { src = Wihf; dst = Wih_bf_f; lb = bx; }
        else if (bx < 128) { src = Wihr; dst = Wih_bf_r; lb = bx - 64; }
        else if (bx < 256) { src = Whhf; dst = Whh_bf_f; lb = bx - 128; }
        else               { src = Whhr; dst = Whh_bf_r; lb = bx - 256; }
        const int b2 = lb * 2048 + tid * 8;
        #pragma unroll
        for (int j = 0; j < 8; ++j) dst[b2 + j] = f2bf(src[b2 + j]);
        return;
    }
    // W_fc transpose: 128x512 -> 512x128
    __shared__ float tile[32][33];
    const int t  = bx - 384;          // 0..63
    const int tilesX = 512 / 32;      // src cols / 32
    const int c0 = (t % tilesX) * 32;
    const int r0 = (t / tilesX) * 32;
    const int tx = threadIdx.x;
    const int ty = threadIdx.y;
    #pragma unroll
    for (int i = ty; i < 32; i += 8)
        tile[i][tx] = Wfc[(size_t)(r0 + i) * 512 + (c0 + tx)];
    __syncthreads();
    #pragma unroll
    for (int i = ty; i < 32; i += 8)
        WfcT[(size_t)(c0 + i) * 128 + (r0 + tx)] = tile[tx][i];
}

// ---------------------------------------------------------------------------
// K2: fused xW prologue + bidirectional LSTM recurrence, bf16 MFMA.
// Grid: 128 blocks = dir(2) x batch(64).  1024 threads = 16 waves.
// M = 32 = the 32 n-sequences of this (dir, b); all blocks run exactly 32
// steps; sequence n's diagonal h extracted at t == n.
// The xW term is rank-1 in n: g[n] = mask[b,n,t]*xW[t] + bias + h[n]@Whh^T.
// xW (32x1024) computed in-block via MFMA (x bf16 @ W_ih^T bf16), cached in
// LDS as bf16.  W_hh streamed from L2 (B-frag direct from [gate][k] layout).
// Wave w owns gate cols {g*256 + w*16 + l15}: all 4 gates of units
// [16w,16w+16) in-lane -> register LSTM epilogue, c-state in VGPRs.
// ---------------------------------------------------------------------------
__global__ __launch_bounds__(1024, 4) void k2_lstm(
    const float* __restrict__ x,
    const float* __restrict__ mask,
    const short* __restrict__ Wih_bf_f, const short* __restrict__ Wih_bf_r,
    const short* __restrict__ Whh_bf_f, const short* __restrict__ Whh_bf_r,
    const float* __restrict__ b_f,  const float* __restrict__ b_r,
    float* __restrict__ y)
{
    constexpr int HP = 264;                    // padded h row (shorts)
    __shared__ short h_lds[2][kN][HP];         // 33 KB
    __shared__ short xw_lds[kN][kG4];          // 64 KB
    __shared__ float mask_lds[kN][33];         // 4.2 KB, padded
    __shared__ short xa[kN][136];              // 8.5 KB x-tile (bf16, padded)

    const int tid  = threadIdx.x;
    const int wave = tid >> 6;                 // 0..15
    const int lane = tid & 63;
    const int quad = lane >> 4;
    const int l15  = lane & 15;

    const int dir = blockIdx.x >> 6;           // 0 fwd, 1 rev
    const int b   = blockIdx.x & 63;

    const short* __restrict__ Wih = dir ? Wih_bf_r : Wih_bf_f;
    const short* __restrict__ Whh = dir ? Whh_bf_r : Whh_bf_f;
    const float* __restrict__ bb  = dir ? b_r : b_f;

    // col bases: gate g, units [16*wave, 16*wave+16)
    int nb[4];
    #pragma unroll
    for (int g = 0; g < 4; ++g) nb[g] = g * kH + wave * 16;

    float bias[4];
    #pragma unroll
    for (int g = 0; g < 4; ++g) bias[g] = bb[nb[g] + l15];

    // ---- stage x (bf16) + mask into LDS ----
    {
        const float* xb = x + (size_t)b * (kN * kDIN);
        #pragma unroll
        for (int i = tid; i < kN * kDIN; i += 1024)
            xa[i >> 7][i & 127] = f2bf(xb[i]);
        const float* mb = mask + (size_t)b * (kN * kN);
        mask_lds[tid >> 5][tid & 31] = mb[tid];
    }
    // zero h buffer 0
    for (int i = tid; i < kN * HP; i += 1024) (&h_lds[0][0][0])[i] = 0;
    __syncthreads();

    // ---- prologue: xw = x @ W_ih^T  (M=32 t-rows, N=1024, K=128) ----
    {
        const short* wpi[4];
        #pragma unroll
        for (int g = 0; g < 4; ++g)
            wpi[g] = Wih + (size_t)(nb[g] + l15) * kDIN + quad * 8;

        f32x4 axw[2][4];
        #pragma unroll
        for (int mt = 0; mt < 2; ++mt)
            #pragma unroll
            for (int g = 0; g < 4; ++g)
                #pragma unroll
                for (int r = 0; r < 4; ++r) axw[mt][g][r] = 0.f;

        #pragma unroll
        for (int kt = 0; kt < 4; ++kt) {
            bf16x8 a0 = *(const bf16x8*)&xa[l15][kt * 32 + quad * 8];
            bf16x8 a1 = *(const bf16x8*)&xa[l15 + 16][kt * 32 + quad * 8];
            #pragma unroll
            for (int g = 0; g < 4; ++g) {
                bf16x8 bf = *(const bf16x8*)(wpi[g] + kt * 32);
                axw[0][g] = __builtin_amdgcn_mfma_f32_16x16x32_bf16(a0, bf, axw[0][g], 0, 0, 0);
                axw[1][g] = __builtin_amdgcn_mfma_f32_16x16x32_bf16(a1, bf, axw[1][g], 0, 0, 0);
            }
        }
        #pragma unroll
        for (int mt = 0; mt < 2; ++mt)
            #pragma unroll
            for (int g = 0; g < 4; ++g)
                #pragma unroll
                for (int r = 0; r < 4; ++r)
                    xw_lds[mt * 16 + quad * 4 + r][nb[g] + l15] = f2bf(axw[mt][g][r]);
    }
    __syncthreads();

    // ---- recurrence ----
    const short* wp[4];
    #pragma unroll
    for (int g = 0; g < 4; ++g)
        wp[g] = Whh + (size_t)(nb[g] + l15) * kH + quad * 8;

    float c[8];
    #pragma unroll
    for (int i = 0; i < 8; ++i) c[i] = 0.f;

    int cur = 0;
    for (int it = 0; it < kN; ++it) {
        const int t = dir ? (kN - 1 - it) : it;

        // init: acc[n, col] = mask[n][t] * xw[t][col] + bias[col]
        float xwv[4];
        #pragma unroll
        for (int g = 0; g < 4; ++g) xwv[g] = bf2f(xw_lds[t][nb[g] + l15]);
        float mk[2][4];
        #pragma unroll
        for (int mt = 0; mt < 2; ++mt)
            #pragma unroll
            for (int r = 0; r < 4; ++r)
                mk[mt][r] = mask_lds[mt * 16 + quad * 4 + r][t];

        f32x4 acc[2][4];
        #pragma unroll
        for (int mt = 0; mt < 2; ++mt)
            #pragma unroll
            for (int g = 0; g < 4; ++g)
                #pragma unroll
                for (int r = 0; r < 4; ++r)
                    acc[mt][g][r] = fmaf(mk[mt][r], xwv[g], bias[g]);

        // K loop: h (LDS) @ W_hh^T (L2 stream)
        #pragma unroll
        for (int kt = 0; kt < 8; ++kt) {
            bf16x8 a0 = *(const bf16x8*)&h_lds[cur][l15][kt * 32 + quad * 8];
            bf16x8 a1 = *(const bf16x8*)&h_lds[cur][l15 + 16][kt * 32 + quad * 8];
            #pragma unroll
            for (int g = 0; g < 4; ++g) {
                bf16x8 bf = *(const bf16x8*)(wp[g] + kt * 32);
                acc[0][g] = __builtin_amdgcn_mfma_f32_16x16x32_bf16(a0, bf, acc[0][g], 0, 0, 0);
                acc[1][g] = __builtin_amdgcn_mfma_f32_16x16x32_bf16(a1, bf, acc[1][g], 0, 0, 0);
            }
        }

        // epilogue: lane owns unit u = wave*16+l15 for 8 n-rows
        const int nxt = cur ^ 1;
        const int u   = wave * 16 + l15;
        #pragma unroll
        for (int mt = 0; mt < 2; ++mt)
            #pragma unroll
            for (int r = 0; r < 4; ++r) {
                const int n  = mt * 16 + quad * 4 + r;
                const int ci = mt * 4 + r;
                const float gI = acc[mt][0][r];
                const float gF = acc[mt][1][r];
                const float gG = acc[mt][2][r];
                const float gO = acc[mt][3][r];
                const float ct = sigm(gF) * c[ci] + sigm(gI) * tanhf(gG);
                c[ci] = ct;
                const float hn = sigm(gO) * tanhf(ct);
                h_lds[nxt][n][u] = f2bf(hn);
                if (n == t)
                    y[((size_t)(b * kN + n)) * (2 * kH) + dir * kH + u] = hn;
            }
        __syncthreads();
        cur = nxt;
    }
}

// ---------------------------------------------------------------------------
// K3: out = relu(y @ W_fc.T + b_fc).  WfcT[k][dout] pre-transposed, fp32.
// ---------------------------------------------------------------------------
__global__ __launch_bounds__(256) void k3_out(
    const float* __restrict__ y, const float* __restrict__ WfcT,
    const float* __restrict__ b_fc, float* __restrict__ out)
{
    __shared__ float ys[8 * 2 * kH];
    const int tid = threadIdx.x;
    const int r0  = blockIdx.x * 8;
    const int col = tid & 127;
    const int rh  = tid >> 7;

    for (int i = tid; i < 8 * 2 * kH / 4; i += 256)
        ((float4*)ys)[i] = ((const float4*)(y + (size_t)r0 * (2 * kH)))[i];
    __syncthreads();

    float acc[4] = {0.f, 0.f, 0.f, 0.f};
    #pragma unroll 4
    for (int k = 0; k < 2 * kH; ++k) {
        const float w = WfcT[(size_t)k * kDOUT + col];
        #pragma unroll
        for (int j = 0; j < 4; ++j)
            acc[j] = fmaf(ys[(rh * 4 + j) * (2 * kH) + k], w, acc[j]);
    }

    const float bias = b_fc[col];
    #pragma unroll
    for (int j = 0; j < 4; ++j) {
        const int row = r0 + rh * 4 + j;
        out[(size_t)row * kDOUT + col] = fmaxf(acc[j] + bias, 0.f);
    }
}

// ---------------------------------------------------------------------------
extern "C" void kernel_launch(void* const* d_in, const int* in_sizes, int n_in,
                              void* d_out, int out_size, void* d_ws, size_t ws_size,
                              hipStream_t stream) {
    const float* x      = (const float*)d_in[0];
    const float* mask   = (const float*)d_in[1];
    const float* W_ih_f = (const float*)d_in[2];
    const float* W_hh_f = (const float*)d_in[3];
    const float* b_f    = (const float*)d_in[4];
    const float* W_ih_r = (const float*)d_in[5];
    const float* W_hh_r = (const float*)d_in[6];
    const float* b_r    = (const float*)d_in[7];
    const float* W_fc   = (const float*)d_in[8];
    const float* b_fc   = (const float*)d_in[9];
    float* out = (float*)d_out;

    short* ws       = (short*)d_ws;
    short* Wih_bf_f = ws;                      // 1024*128 bf16
    short* Wih_bf_r = Wih_bf_f + 131072;
    short* Whh_bf_f = Wih_bf_r + 131072;       // 1024*256 bf16
    short* Whh_bf_r = Whh_bf_f + 262144;
    float* WfcT     = (float*)(Whh_bf_r + 262144);   // 512*128 f
    float* yb       = WfcT + 65536;            // 2048*512 f

    prep_k<<<448, dim3(32, 8), 0, stream>>>(
        W_ih_f, W_ih_r, W_hh_f, W_hh_r, W_fc,
        Wih_bf_f, Wih_bf_r, Whh_bf_f, Whh_bf_r, WfcT);

    k2_lstm<<<128, 1024, 0, stream>>>(
        x, mask, Wih_bf_f, Wih_bf_r, Whh_bf_f, Whh_bf_r, b_f, b_r, yb);

    k3_out<<<kBN / 8, 256, 0, stream>>>(yb, WfcT, b_fc, out);
}